// Round 8
// baseline (100.996 us; speedup 1.0000x reference)
//
#include <hip/hip_runtime.h>

// Exact KNN (faiss-equivalent, (dist,idx)-lexicographic ties) + fused neighbor
// feature sum. N=65536 pts on 128^3 int grid, K=16, C=64.
//
// Cells = 4^3 coords -> 32^3 = 32768 cells, ~2 pts/cell. Key = (d2<<16)|idx
// (d2 <= 48387 < 2^16): unsigned order == (dist, idx) lexicographic.
//
// PROLOGUE lessons (r1-r6): no grid barriers (~8us each regardless of poll
// discipline); no high-multiplicity same-address atomics (~100ns per RMW);
// deterministic cell-ordered layout via contention-free chunk_reduce +
// per-chunk scan. 5 slim dispatches, driver ordering.
//
// KNN lessons (r0-r7): duration pinned at ~42us across configs varying VALU
// +-50%, waves 2x, load width 2x -> per-query GLOBAL latency chains + 67MB
// of per-query re-read L2 traffic, unhidden at any achievable TLP.
// r8: REGION BLOCKS. Block = aligned 4x4x4-cell region (~128 queries).
// Stage the 8x8x8-cell candidate superset (~1024 pts) in LDS once (global
// scan traffic 67MB -> 4MB); every query's shift-clamped 4x4x4 quadrant box
// is provably inside the superset (box origin in [c-2,c-1] clamped [0,28]),
// so the coverage guarantee (uncovered min-d2 >= 49) is unchanged.
// Lane = whole query: scans its ~128 candidates from LDS into a private
// sorted top-16 (med3 insert network) -> NO merge tree, no slices; k[15] is
// directly the redo bound. Boundary table (64 rows x 9, ushort, LDS-relative)
// gives each row scan as a tight LDS loop. Safety: candidate overflow
// (P~1e-80) -> per-lane global-scan fallback; redo (P~1e-7/query) ->
// per-lane serial cube r<=2 + Chebyshev shells r>=3 ((4r-3)^2 bound), exact.
// Gather: top-16 staged to LDS table; passes of 4 queries x 16 ch-lanes;
// float4 feature rows; direct output write.

typedef unsigned int uint;
typedef unsigned short ushort;
typedef short short2v __attribute__((ext_vector_type(2)));

#define NPTS     65536
#define NCELL    32768
#define CAND_CAP 1664
#define QCAP     512

static __device__ inline short2v u2s(uint v) { union { uint u; short2v s; } c; c.u = v; return c.s; }
static __device__ inline uint s2u(short2v v) { union { uint u; short2v s; } c; c.s = v; return c.u; }

static __device__ inline int dot2acc(short2v a, short2v b, int c) {
#if __has_builtin(__builtin_amdgcn_sdot2)
    return __builtin_amdgcn_sdot2(a, b, c, false);
#else
    return (int)a.x * (int)b.x + (int)a.y * (int)b.y + c;
#endif
}

__global__ __launch_bounds__(256) void cell_count(const int* __restrict__ coords,
                                                  uint* __restrict__ counts) {
    int i = blockIdx.x * 256 + threadIdx.x;
    int x = coords[3 * i + 0], y = coords[3 * i + 1], z = coords[3 * i + 2];
    int cell = (x >> 2) | ((y >> 2) << 5) | ((z >> 2) << 10);
    atomicAdd(&counts[cell], 1u);
}

// Contention-free chunk totals: block j reduces its 256 counts (coalesced),
// one plain store. No atomics.
__global__ __launch_bounds__(256) void chunk_reduce(const uint* __restrict__ counts,
                                                    uint* __restrict__ chunktot) {
    __shared__ uint wsum[4];
    int tid = threadIdx.x;
    int lane = tid & 63, wv = tid >> 6;
    uint c = counts[blockIdx.x * 256 + tid];
#pragma unroll
    for (int off = 32; off; off >>= 1) c += __shfl_xor(c, off, 64);
    if (lane == 0) wsum[wv] = c;
    __syncthreads();
    if (tid == 0) chunktot[blockIdx.x] = wsum[0] + wsum[1] + wsum[2] + wsum[3];
}

// Deterministic cell-ordered scan, no grid barrier: chunk base = reduce of
// chunktot[0..chunk), + block-local scan of 256 cells.
__global__ __launch_bounds__(256) void scan_chunk(const uint* __restrict__ counts,
                                                  const uint* __restrict__ chunktot,
                                                  uint* __restrict__ starts,
                                                  uint* __restrict__ cursors) {
    __shared__ uint wsum[4];
    int b = blockIdx.x;
    int tid = threadIdx.x;
    int lane = tid & 63, wv = tid >> 6;
    int cell = b * 256 + tid;

    uint t0 = chunktot[lane];
    uint t1 = chunktot[64 + lane];
    uint s = (lane < b ? t0 : 0u) + (64 + lane < b ? t1 : 0u);
#pragma unroll
    for (int off = 32; off; off >>= 1) s += __shfl_xor(s, off, 64);
    uint base = s;

    uint c = counts[cell];
    uint v = c;
#pragma unroll
    for (int off = 1; off < 64; off <<= 1) {
        uint u = __shfl_up(v, off, 64);
        if (lane >= off) v += u;
    }
    if (lane == 63) wsum[wv] = v;
    __syncthreads();
    uint woff = 0;
#pragma unroll
    for (int j = 0; j < 4; ++j) woff += (j < wv) ? wsum[j] : 0u;
    uint st = base + woff + v - c;
    starts[cell]  = st;
    cursors[cell] = st;
    if (cell == NCELL - 1) starts[NCELL] = st + c;   // = 65536
}

__global__ __launch_bounds__(256) void cell_scatter(const int* __restrict__ coords,
                                                    uint* __restrict__ cursors,
                                                    uint2* __restrict__ sorted) {
    int i = blockIdx.x * 256 + threadIdx.x;
    int x = coords[3 * i + 0], y = coords[3 * i + 1], z = coords[3 * i + 2];
    int cell = (x >> 2) | ((y >> 2) << 5) | ((z >> 2) << 10);
    uint pos = atomicAdd(&cursors[cell], 1u);
    // packed: w0 = x | y<<16, w1 = idx | z<<16
    sorted[pos] = make_uint2((uint)(x | (y << 16)), (uint)(i | (z << 16)));
}

__global__ __launch_bounds__(256, 2) void knn_region(const uint* __restrict__ starts,
                                                     const uint2* __restrict__ sorted,
                                                     const float* __restrict__ feat,
                                                     float* __restrict__ out) {
    __shared__ uint2  cand[CAND_CAP];    // staged 8x8x8-cell candidates
    __shared__ uint   rowlo[65];         // row -> LDS offset (exclusive prefix)
    __shared__ uint   rowgs[64];         // row -> global start
    __shared__ ushort bnd[64][9];        // row x cell -> LDS boundary
    __shared__ uint   qlist[QCAP];       // global positions of region queries
    __shared__ uint   gt[256 * 17];      // gather table: qidx + 16 neighbor ids
    __shared__ uint   nq_sh, stot_sh;

    // XCD-chunked swizzle: consecutive logical regions -> same XCD.
    int b = (blockIdx.x & 7) * 64 + (blockIdx.x >> 3);   // 512 regions
    int Rx = (b & 7) * 4, Ry = ((b >> 3) & 7) * 4, Rz = (b >> 6) * 4;
    int x0  = max(Rx - 2, 0); int nx = min(Rx + 6, 32) - x0;
    int ys0 = max(Ry - 2, 0); int ny = min(Ry + 6, 32) - ys0;
    int zs0 = max(Rz - 2, 0); int nz = min(Rz + 6, 32) - zs0;

    int tid = threadIdx.x, lane = tid & 63, wv = tid >> 6;

    if (wv == 0) {
        // row lengths + prefix (row r = zi*8+yi; staged x-range [x0, x0+nx))
        int yi = lane & 7, zi = lane >> 3;
        bool valid = (yi < ny) && (zi < nz);
        uint gs = 0, len = 0;
        if (valid) {
            int rb = ((ys0 + yi) << 5) | ((zs0 + zi) << 10);
            gs  = starts[rb + x0];
            len = starts[rb + x0 + nx] - gs;   // contiguous global layout
        }
        uint v = len;
#pragma unroll
        for (int off = 1; off < 64; off <<= 1) {
            uint u = __shfl_up(v, off, 64);
            if (lane >= off) v += u;
        }
        rowlo[lane] = v - len;
        rowgs[lane] = gs;
        if (lane == 63) { rowlo[64] = v; stot_sh = v; }
    } else if (wv == 1 && lane < 16) {
        // region query list: 16 center rows, 4 center x-cells each (contiguous)
        int qy = lane & 3, qz = lane >> 2;
        int rb = ((Ry + qy) << 5) | ((Rz + qz) << 10);
        uint g0  = starts[rb + Rx];
        uint len = starts[rb + Rx + 4] - g0;
        uint v = len;
#pragma unroll
        for (int off = 1; off < 16; off <<= 1) {
            uint u = __shfl_up(v, off, 64);
            if (lane >= off) v += u;
        }
        uint e0 = v - len;
        for (uint j = 0; j < len; ++j)
            if (e0 + j < QCAP) qlist[e0 + j] = g0 + j;
        if (lane == 15) nq_sh = min(v, (uint)QCAP);
    }
    __syncthreads();

    uint stot = stot_sh;
    bool ofl  = stot > CAND_CAP;          // P ~ 0 (Poisson(1024), 18+ sigma)
    uint nq   = nq_sh;

    // boundary table (LDS-relative) + staging copy
    for (int e = tid; e < 576; e += 256) {
        int r = e / 9, i = e - r * 9;
        int yi = r & 7, zi = r >> 3;
        if (yi < ny && zi < nz && i <= nx) {
            int rb = ((ys0 + yi) << 5) | ((zs0 + zi) << 10);
            bnd[r][i] = (ushort)(rowlo[r] + (starts[rb + x0 + i] - rowgs[r]));
        }
    }
    if (!ofl) {
        for (int r = wv; r < 64; r += 4) {
            uint lo = rowlo[r], len = rowlo[r + 1] - lo, gs = rowgs[r];
            for (uint p = lane; p < len; p += 64) cand[lo + p] = sorted[gs + p];
        }
    }
    __syncthreads();

    for (uint cbase = 0; cbase < nq; cbase += 256) {
        bool have = (cbase + (uint)tid) < nq;
        uint k[16];
#pragma unroll
        for (int j = 0; j < 16; ++j) k[j] = 0xFFFFFFFFu;

        uint qxy = 0, qzp = 0, qidx = 0;
        int qx = 0, qy = 0, qz = 0, cx = 0, cy = 0, cz = 0;
        if (have) {
            uint2 me = sorted[qlist[cbase + tid]];
            qxy = me.x; qzp = me.y & 0xFFFF0000u; qidx = me.y & 0xFFFFu;
            qx = (int)(me.x & 0xFFFFu); qy = (int)(me.x >> 16); qz = (int)(me.y >> 16);
            cx = qx >> 2; cy = qy >> 2; cz = qz >> 2;
        }

        auto insert1 = [&](uint2 pt) {
            short2v A = u2s(pt.x) - u2s(qxy);
            short2v B = u2s(pt.y) - u2s(qzp);
            uint Bu = s2u(B);
            short2v Bm = u2s(Bu & 0xFFFF0000u);
            int d2 = dot2acc(A, A, dot2acc(Bm, Bm, 0));
            uint key = ((uint)d2 << 16) + (Bu & 0xFFFFu);
#pragma unroll
            for (int j = 15; j >= 1; --j)
                asm("v_med3_u32 %0, %1, %2, %3"
                    : "=v"(k[j]) : "v"(k[j - 1]), "v"(k[j]), "v"(key));
            k[0] = min(k[0], key);
        };

        // ---- quadrant-aligned 4x4x4 box, SHIFT-clamped; box is always
        //      inside the staged 8x8x8 superset (proof in header) ----
        int xa = min(max(cx - ((qx & 3) < 2 ? 2 : 1), 0), 28);
        int ya = min(max(cy - ((qy & 3) < 2 ? 2 : 1), 0), 28);
        int za = min(max(cz - ((qz & 3) < 2 ? 2 : 1), 0), 28);

        if (have) {
            if (!ofl) {
                int i0 = xa - x0, ry0 = ya - ys0, rz0 = za - zs0;
#pragma unroll
                for (int rz = 0; rz < 4; ++rz)
#pragma unroll
                    for (int ry = 0; ry < 4; ++ry) {
                        int r = (rz0 + rz) * 8 + (ry0 + ry);
                        uint p0 = bnd[r][i0], p1 = bnd[r][i0 + 4];
                        for (uint p = p0; p < p1; ++p) insert1(cand[p]);
                    }
            } else {
                for (int rz = 0; rz < 4; ++rz)
                    for (int ry = 0; ry < 4; ++ry) {
                        int rb = ((ya + ry) << 5) | ((za + rz) << 10);
                        uint p1 = starts[rb + xa + 4];
                        for (uint p = starts[rb + xa]; p < p1; ++p) insert1(sorted[p]);
                    }
            }
        }

        // ---- cold redo (k sorted ascending -> k[15] is the bound) ----
        bool redo = have && ((k[15] >> 16) >= 49u);
        if (__any(redo)) {
            if (redo) {
#pragma unroll
                for (int j = 0; j < 16; ++j) k[j] = 0xFFFFFFFFu;
                int xl = max(cx - 2, 0), xh = min(cx + 2, 31);
                int yl = max(cy - 2, 0), yh = min(cy + 2, 31);
                int zl = max(cz - 2, 0), zh = min(cz + 2, 31);
                for (int z = zl; z <= zh; ++z)
                    for (int y = yl; y <= yh; ++y) {
                        int rb = (y << 5) | (z << 10);
                        uint p1 = starts[rb + xh + 1];
                        for (uint p = starts[rb + xl]; p < p1; ++p) insert1(sorted[p]);
                    }
                for (int r = 3; r < 32; ++r) {
                    uint bb = (uint)(4 * r - 3);
                    if ((k[15] >> 16) < bb * bb) break;
                    int z0 = max(cz - r, 0), z1 = min(cz + r, 31);
                    for (int z = z0; z <= z1; ++z) {
                        bool zface = (z == cz - r) || (z == cz + r);
                        int y0 = max(cy - r, 0), y1 = min(cy + r, 31);
                        for (int y = y0; y <= y1; ++y) {
                            bool face = zface || (y == cy - r) || (y == cy + r);
                            int rb = (y << 5) | (z << 10);
                            if (face) {
                                int xf0 = max(cx - r, 0), xf1 = min(cx + r, 31);
                                uint p1 = starts[rb + xf1 + 1];
                                for (uint p = starts[rb + xf0]; p < p1; ++p) insert1(sorted[p]);
                            } else {
                                int xL = cx - r;
                                if (xL >= 0) {
                                    uint p1 = starts[rb + xL + 1];
                                    for (uint p = starts[rb + xL]; p < p1; ++p) insert1(sorted[p]);
                                }
                                int xR = cx + r;
                                if (xR <= 31) {
                                    uint p1 = starts[rb + xR + 1];
                                    for (uint p = starts[rb + xR]; p < p1; ++p) insert1(sorted[p]);
                                }
                            }
                        }
                    }
                }
            }
        }

        // ---- stage top-16 sets, then cooperative gather ----
        if (have) {
            gt[tid * 17] = qidx;
#pragma unroll
            for (int j = 0; j < 16; ++j) gt[tid * 17 + 1 + j] = k[j] & 0xFFFFu;
        }
        __syncthreads();

        uint cn = min(nq - cbase, 256u);
        int ch = lane & 15, qg = lane >> 4;
        for (uint ps = wv; ps * 4 < cn; ps += 4) {
            uint qs = ps * 4 + (uint)qg;
            if (qs < cn) {
                uint qorig = gt[qs * 17];
                float4 acc = make_float4(0.f, 0.f, 0.f, 0.f);
#pragma unroll
                for (int j = 0; j < 16; ++j) {
                    uint nj = gt[qs * 17 + 1 + j];
                    float4 v = reinterpret_cast<const float4*>(feat)[nj * 16u + (uint)ch];
                    acc.x += v.x; acc.y += v.y; acc.z += v.z; acc.w += v.w;
                }
                reinterpret_cast<float4*>(out)[qorig * 16u + (uint)ch] = acc;
            }
        }
        __syncthreads();
    }
}

extern "C" void kernel_launch(void* const* d_in, const int* in_sizes, int n_in,
                              void* d_out, int out_size, void* d_ws, size_t ws_size,
                              hipStream_t stream) {
    const int*   coords = (const int*)d_in[0];
    const float* feat   = (const float*)d_in[1];
    float*       out    = (float*)d_out;

    uint* W = (uint*)d_ws;
    uint*  chunktot = W;                      // 128 (written by chunk_reduce)
    uint*  counts   = W + 128;                // 32768, memset-zeroed
    uint*  starts   = W + 32896;              // 32769
    uint*  cursors  = W + 65668;              // 32768
    uint2* sorted   = (uint2*)(W + 98436);    // 65536 entries (+1 pad slack)

    hipMemsetAsync(counts, 0, NCELL * sizeof(uint), stream);
    cell_count<<<NPTS / 256, 256, 0, stream>>>(coords, counts);
    chunk_reduce<<<NCELL / 256, 256, 0, stream>>>(counts, chunktot);
    scan_chunk<<<NCELL / 256, 256, 0, stream>>>(counts, chunktot, starts, cursors);
    cell_scatter<<<NPTS / 256, 256, 0, stream>>>(coords, cursors, sorted);
    knn_region<<<512, 256, 0, stream>>>(starts, sorted, feat, out);
}